// Round 1
// 94.658 us; speedup vs baseline: 1.0009x; 1.0009x over previous
//
#include <hip/hip_runtime.h>

// B=64, T=256, D=128, H=8, E=128, H*E=1024.
// Algebra (verified R1-R6): with xw[b]=Ws^T x[b], Sw=sum(Ws):
//   Kw[b,he]   = xw[b] @ Wk[:,he] + Sw*bk[he]
//   wqk[b,h,d] = scale * sum_e Wq[d,h*128+e]*Kw[b,h,e]   (bq, bs drop: shift-invariant)
//   beta[b,h,t]= softmax_t( x[b,t] . wqk[b,h] )
//   xb[b,h,d]  = sum_t beta[b,h,t]*x[b,t,d]
//   res[b,he]  = xb[b,h] @ Wv[:,he] + bv[he]             (sum_t beta = 1)
//   out[b,d']  = res[b] @ Wo[:,d'] + bo[d']
//
// R8 = R7 skeleton + LDS-resident x:
//  (1) x[b] (128KB) staged ONCE into LDS via global_load_lds (16B, linear dest);
//      phases A/D/E read it from LDS. Cuts per-block L2 traffic 896->640KB and
//      removes the rxd/rxe prefetch windows. Both read patterns put exactly 8
//      lanes per 16B bank-quad (row stride 512B % 128B == 0) = ds_read_b128
//      floor, so NO padding (which would break global_load_lds linearity).
//  (2) entry: ws-copy -> 16x global_load_lds -> 16x Wk dwordx4, pinned with
//      sched_barrier(0); `s_waitcnt vmcnt(16)` + s_barrier completes the LDS-DMA
//      while Wk's 16 loads STAY IN FLIGHT across the barrier (R7 fix preserved).
//  (3) freed registers: Wv prefetch moved E->C, Wo F->E. Every prefetch now has
//      >=2 phases of cover; still max 2 live 16xfloat4 arrays (VGPR ~170).

#define SCALE 0.08838834764831845f  // 1/sqrt(128)
#define MAGIC 0x13579BDFu

// LDS-ordering barrier that does NOT drain vmcnt (global loads stay in flight).
#define BAR() __asm__ volatile("s_waitcnt lgkmcnt(0)\n\ts_barrier" ::: "memory")

typedef const __attribute__((address_space(1))) void gvoid_t;
typedef __attribute__((address_space(3))) void lvoid_t;

__global__ __launch_bounds__(512)
void ta_one(const float* __restrict__ x,  const float* __restrict__ Wq,
            const float* __restrict__ Wk, const float* __restrict__ bk,
            const float* __restrict__ Wv, const float* __restrict__ bv,
            const float* __restrict__ Wsv,
            const float* __restrict__ Wo, const float* __restrict__ bov,
            float* __restrict__ ws, float* __restrict__ out)
{
    __shared__ __align__(16) float xS[32768];     // x[b] [t][d], 131072 B
    __shared__ __align__(16) float pA[2056];      // partials (stride 257 for C/D)
    __shared__ __align__(16) float pB[2056];
    __shared__ __align__(16) float wsS[256];
    __shared__ __align__(16) float xwS[128];
    __shared__ __align__(16) float kwS[256];      // [hi][e]
    __shared__ __align__(16) float wqkS[256];     // [hi][d], pre-scaled
    __shared__ __align__(16) float betaS[2][256];
    __shared__ __align__(16) float xbS[256];      // [hi][d]
    __shared__ __align__(16) float resS[256];
    __shared__ float smx[2][4], sms[2][4];
    __shared__ float swS;
    // total: 131072+8224+8224+1024+512+1024+1024+2048+1024+1024+64+4 = 155268 B <= 160 KiB

    const int tid = threadIdx.x;
    const int b = blockIdx.x, p = blockIdx.y;
    const int w = tid >> 6, l = tid & 63;
    const float* xp0 = x + (size_t)b * 32768;

    const int q5 = tid & 31, tc = tid >> 5;   // col-stream A/E/G: lane=4d, 16 chunks
    const int q6 = tid & 63, kh = tid >> 6;   // col-stream B/F: lane=4he, 8 chunks
    const int c8 = tid & 7,  r8 = tid >> 3;   // row-dot C/D: chunk c8, row-set r8

    // ---------- entry: ws table, x -> LDS (DMA), Wk -> regs ----------
    if (tid < 64) *(float4*)(wsS + 4 * tid) = *(const float4*)(Wsv + 4 * tid);
    __builtin_amdgcn_sched_barrier(0);
    {   // stage x[b]: 128 rows of 1KB; wave w, iter j copies row j*8+w, lane l -> +16B
        #pragma unroll
        for (int j = 0; j < 16; ++j) {
            const int blk = j * 8 + w;
            __builtin_amdgcn_global_load_lds(
                (gvoid_t*)((const char*)xp0 + blk * 1024 + l * 16),
                (lvoid_t*)((char*)xS + blk * 1024), 16, 0, 0);
        }
    }
    __builtin_amdgcn_sched_barrier(0);
    float4 rwk[16];
    {
        const float4* wp = (const float4*)(Wk + (size_t)(kh * 16) * 1024 + 256 * p + 4 * q6);
        #pragma unroll
        for (int j = 0; j < 16; ++j) rwk[j] = wp[(size_t)j * 256];
    }
    __builtin_amdgcn_sched_barrier(0);
    // xS DMA (+ws load) complete; the 16 newest (Wk dwordx4) remain in flight.
    __asm__ volatile("s_waitcnt vmcnt(16) lgkmcnt(0)\n\ts_barrier" ::: "memory");

    // ---------- A: xw partials (reads xS) ----------
    {
        const float* xrow = xS + (tc * 16) * 128 + 4 * q5;
        float4 acc = {0.f, 0.f, 0.f, 0.f};
        #pragma unroll
        for (int j = 0; j < 16; ++j) {
            const float s = wsS[tc * 16 + j];
            const float4 xv = *(const float4*)(xrow + j * 128);
            acc.x += s * xv.x; acc.y += s * xv.y;
            acc.z += s * xv.z; acc.w += s * xv.w;
        }
        *(float4*)(pA + tc * 128 + 4 * q5) = acc;
    }
    // prefetch C's Wq row-chunks (cold) — interleaved mapping: 8 lanes = 128B
    float4 rwq[16];
    {
        #pragma unroll
        for (int rr = 0; rr < 4; ++rr) {
            const int o = r8 + 64 * rr;            // o = hi*128+d
            const float* base = Wq + (size_t)(o & 127) * 1024 + (2 * p + (o >> 7)) * 128;
            #pragma unroll
            for (int jj = 0; jj < 4; ++jj)
                rwq[rr * 4 + jj] = *(const float4*)(base + (jj * 8 + c8) * 4);
        }
    }
    const float bkv = bk[256 * p + (tid & 255)];   // used at B-reduce (3 phases away)
    const float bvv = bv[256 * p + (tid & 255)];   // used at F-reduce
    BAR();
    if (tid < 128) {
        float v = 0.f;
        #pragma unroll
        for (int g = 0; g < 16; ++g) v += pA[g * 128 + tid];
        xwS[tid] = v;
    } else if (tid < 192) {                        // Sw
        float v = wsS[l] + wsS[l + 64] + wsS[l + 128] + wsS[l + 192];
        #pragma unroll
        for (int off = 32; off; off >>= 1) v += __shfl_xor(v, off, 64);
        if (l == 0) swS = v;
    }
    BAR();

    // ---------- B: Kw partials (uses rwk; dies) ----------
    {
        float4 acc = {0.f, 0.f, 0.f, 0.f};
        #pragma unroll
        for (int j = 0; j < 16; ++j) {
            const float xv = xwS[kh * 16 + j];
            acc.x += xv * rwk[j].x; acc.y += xv * rwk[j].y;
            acc.z += xv * rwk[j].z; acc.w += xv * rwk[j].w;
        }
        *(float4*)(pB + kh * 256 + 4 * q6) = acc;
    }
    // prefetch F's Wv (cold) — moved E->C: covered by B-reduce, C, D, softmax, E
    float4 rwv[16];
    {
        const float4* wp = (const float4*)(Wv + (size_t)(kh * 16) * 1024 + 256 * p + 4 * q6);
        #pragma unroll
        for (int j = 0; j < 16; ++j) rwv[j] = wp[(size_t)j * 256];
    }
    BAR();
    if (tid < 256) {
        float v = swS * bkv;
        #pragma unroll
        for (int g = 0; g < 8; ++g) v += pB[g * 256 + tid];
        kwS[tid] = v;
    }
    BAR();

    // ---------- C: wqk row-dots (uses rwq; dies) ----------
    {
        #pragma unroll
        for (int rr = 0; rr < 4; ++rr) {
            const int o = r8 + 64 * rr;
            const float* kp = kwS + (o >> 7) * 128;
            float a = 0.f;
            #pragma unroll
            for (int jj = 0; jj < 4; ++jj) {
                const float4 wv = rwq[rr * 4 + jj];
                const float* kk = kp + (jj * 8 + c8) * 4;
                a += wv.x * kk[0] + wv.y * kk[1] + wv.z * kk[2] + wv.w * kk[3];
            }
            pA[c8 * 257 + o] = a;
        }
    }
    BAR();
    if (tid < 256) {
        float v = 0.f;
        #pragma unroll
        for (int g = 0; g < 8; ++g) v += pA[g * 257 + tid];
        wqkS[tid] = v * SCALE;
    }
    BAR();

    // ---------- D: score row-dots (reads xS; 8 lanes/bank-quad = b128 floor) ----------
    {
        #pragma unroll
        for (int rr = 0; rr < 4; ++rr) {
            const int t = r8 + 64 * rr;
            const float* xrow = xS + t * 128;
            float a0 = 0.f, a1 = 0.f;
            #pragma unroll
            for (int jj = 0; jj < 4; ++jj) {
                const float4 xv = *(const float4*)(xrow + (jj * 8 + c8) * 4);
                const float* q0 = wqkS + (jj * 8 + c8) * 4;
                const float* q1 = wqkS + 128 + (jj * 8 + c8) * 4;
                a0 += xv.x * q0[0] + xv.y * q0[1] + xv.z * q0[2] + xv.w * q0[3];
                a1 += xv.x * q1[0] + xv.y * q1[1] + xv.z * q1[2] + xv.w * q1[3];
            }
            pA[c8 * 257 + t] = a0;
            pB[c8 * 257 + t] = a1;
        }
    }
    BAR();

    // ---------- softmax over t per head (thread = (hi, t)) ----------
    {
        const int t = tid & 255, hi = tid >> 8;
        const float* pS = hi ? pB : pA;
        float v = 0.f;
        #pragma unroll
        for (int g = 0; g < 8; ++g) v += pS[g * 257 + t];
        float m = v;
        #pragma unroll
        for (int off = 32; off; off >>= 1) m = fmaxf(m, __shfl_xor(m, off, 64));
        if (l == 0) smx[hi][w & 3] = m;
        BAR();
        const float M = fmaxf(fmaxf(smx[hi][0], smx[hi][1]), fmaxf(smx[hi][2], smx[hi][3]));
        const float e = __expf(v - M);
        float ssum = e;
        #pragma unroll
        for (int off = 32; off; off >>= 1) ssum += __shfl_xor(ssum, off, 64);
        if (l == 0) sms[hi][w & 3] = ssum;
        BAR();
        const float S = sms[hi][0] + sms[hi][1] + sms[hi][2] + sms[hi][3];
        betaS[hi][t] = e / S;
    }
    BAR();

    // ---------- E: xb partials (reads xS) ----------
    {
        const float* xrow = xS + (tc * 16) * 128 + 4 * q5;
        float4 a0 = {0.f,0.f,0.f,0.f}, a1 = {0.f,0.f,0.f,0.f};
        #pragma unroll
        for (int j = 0; j < 16; ++j) {
            const float b0 = betaS[0][tc * 16 + j], b1 = betaS[1][tc * 16 + j];
            const float4 xv = *(const float4*)(xrow + j * 128);
            a0.x += b0 * xv.x; a0.y += b0 * xv.y;
            a0.z += b0 * xv.z; a0.w += b0 * xv.w;
            a1.x += b1 * xv.x; a1.y += b1 * xv.y;
            a1.z += b1 * xv.z; a1.w += b1 * xv.w;
        }
        *(float4*)(pA + tc * 128 + 4 * q5) = a0;
        *(float4*)(pB + tc * 128 + 4 * q5) = a1;
    }
    // prefetch G's Wo (cold) — moved F->E: covered by E-reduce and F
    float4 rwo[16];
    {
        const float4* wp = (const float4*)(Wo + (size_t)(256 * p + tc * 16) * 128 + 4 * q5);
        #pragma unroll
        for (int j = 0; j < 16; ++j) rwo[j] = wp[(size_t)j * 32];
    }
    BAR();
    if (tid < 256) {
        const int hi = tid >> 7, d = tid & 127;
        const float* pp = hi ? pB : pA;
        float v = 0.f;
        #pragma unroll
        for (int g = 0; g < 16; ++g) v += pp[g * 128 + d];
        xbS[tid] = v;
    }
    BAR();

    // ---------- F: res partials (uses rwv; dies) ----------
    {
        const int hi = q6 >> 5;
        float4 acc = {0.f, 0.f, 0.f, 0.f};
        #pragma unroll
        for (int j = 0; j < 16; ++j) {
            const float xv = xbS[hi * 128 + kh * 16 + j];
            acc.x += xv * rwv[j].x; acc.y += xv * rwv[j].y;
            acc.z += xv * rwv[j].z; acc.w += xv * rwv[j].w;
        }
        *(float4*)(pB + kh * 256 + 4 * q6) = acc;
    }
    BAR();
    if (tid < 256) {
        float v = bvv;
        #pragma unroll
        for (int g = 0; g < 8; ++g) v += pB[g * 256 + tid];
        resS[tid] = v;
    }
    BAR();

    // ---------- G: out-partials (uses rwo; dies) ----------
    {
        float4 acc = {0.f, 0.f, 0.f, 0.f};
        #pragma unroll
        for (int j = 0; j < 16; ++j) {
            const float rv = resS[tc * 16 + j];
            acc.x += rv * rwo[j].x; acc.y += rv * rwo[j].y;
            acc.z += rv * rwo[j].z; acc.w += rv * rwo[j].w;
        }
        *(float4*)(pA + tc * 128 + 4 * q5) = acc;
    }
    __syncthreads();   // full barrier before handshake (global-store ordering next)

    // ---------- cross-block reduce over p (ws poisoned 0xAA each call) ----------
    float* part = ws;                               // [64*4*128]
    unsigned* flags = (unsigned*)(ws + 32768);      // [256]
    if (p < 3) {
        if (tid < 128) {
            float v = 0.f;
            #pragma unroll
            for (int g = 0; g < 16; ++g) v += pA[g * 128 + tid];
            part[(size_t)(b * 4 + p) * 128 + tid] = v;
            __threadfence();
        }
        __syncthreads();
        if (tid == 0) atomicExch(&flags[b * 4 + p], MAGIC);
    } else {
        if (tid == 0) {
            while (atomicCAS(&flags[b * 4 + 0], MAGIC, MAGIC) != MAGIC) {}
            while (atomicCAS(&flags[b * 4 + 1], MAGIC, MAGIC) != MAGIC) {}
            while (atomicCAS(&flags[b * 4 + 2], MAGIC, MAGIC) != MAGIC) {}
        }
        __syncthreads();
        if (tid < 128) {
            float v = bov[tid];
            #pragma unroll
            for (int g = 0; g < 16; ++g) v += pA[g * 128 + tid];
            v += atomicAdd(&part[(size_t)(b * 4 + 0) * 128 + tid], 0.f);
            v += atomicAdd(&part[(size_t)(b * 4 + 1) * 128 + tid], 0.f);
            v += atomicAdd(&part[(size_t)(b * 4 + 2) * 128 + tid], 0.f);
            out[(size_t)b * 128 + tid] = v;
        }
    }
}

extern "C" void kernel_launch(void* const* d_in, const int* in_sizes, int n_in,
                              void* d_out, int out_size, void* d_ws, size_t ws_size,
                              hipStream_t stream) {
    const float* x  = (const float*)d_in[0];
    const float* Wq = (const float*)d_in[1];
    // d_in[2] = bq  — softmax shift-invariant, unused
    const float* Wk = (const float*)d_in[3];
    const float* bk = (const float*)d_in[4];
    const float* Wv = (const float*)d_in[5];
    const float* bv = (const float*)d_in[6];
    const float* Ws = (const float*)d_in[7];
    // d_in[8] = bs  — softmax shift-invariant, unused
    const float* Wo = (const float*)d_in[9];
    const float* bo = (const float*)d_in[10];
    float* out = (float*)d_out;
    float* ws  = (float*)d_ws;

    ta_one<<<dim3(64, 4), dim3(512), 0, stream>>>(x, Wq, Wk, bk, Wv, bv, Ws, Wo, bo, ws, out);
}